// Round 7
// baseline (890.801 us; speedup 1.0000x reference)
//
#include <hip/hip_runtime.h>
#include <hip/hip_bf16.h>

#define NPIX   65536
#define TT     5
#define CC     10
#define HH     32
#define WIDTH  64
#define KW     32
#define OUTC   10

// ---- workspace layout (float offsets) ----
#define OFF_L0I    0        // 1280  [j][c] float4 gates (i,f,g,o)
#define OFF_L0H    1280     // 4096  [j][k] float4
#define OFF_L1I    5376     // 4096
#define OFF_L1H    9472     // 4096
#define OFF_B0     13568    // 128
#define OFF_B1     13696    // 128
#define LSTM_STAGE_F4 3456  // 13824 floats / 4
#define OFF_FC1W   13824    // 2048  [ch2][k] float2
#define OFF_FC1B   15872    // 64
#define OFF_CWT2   16384    // 16384 [k][co2][ci] float2
#define OFF_CB     32768    // 256
#define OFF_FC2W2  33024    // 2048  [m2][ch] float2
#define OFF_FC2B   35072    // 32
#define OFF_FC3W4  35104    // 320   [oc2][m2] float4
#define OFF_FC3B   35424    // 16
#define OFF_GW     35440    // 8
#define OFF_FEATS_A 36864
#define OFF_FEATS_B (36864 + 8388608)

#define STRAIGHT_ATTR_IDX (65025 * 3)

__device__ __forceinline__ float sigf(float x)  { return 1.0f / (1.0f + __expf(-x)); }
__device__ __forceinline__ float tanhf_(float x){ return 1.0f - 2.0f / (__expf(2.0f * x) + 1.0f); }
__device__ __forceinline__ float4 fma4(float4 q, float s, float4 a) {
    a.x = __builtin_fmaf(q.x, s, a.x);
    a.y = __builtin_fmaf(q.y, s, a.y);
    a.z = __builtin_fmaf(q.z, s, a.z);
    a.w = __builtin_fmaf(q.w, s, a.w);
    return a;
}

// ---------------- prep (same packing as R5/R6) ----------------
__global__ __launch_bounds__(256, 1)
void prep_kernel(const float* Wih0, const float* Whh0,
                 const float* bih0, const float* bhh0,
                 const float* Wih1, const float* Whh1,
                 const float* bih1, const float* bhh1,
                 const float* fc1w, const float* fc1b,
                 const float* convw, const float* convb,
                 const float* fc2w, const float* fc2b,
                 const float* fc3w, const float* fc3b,
                 const float* gparam, const float* eattr,
                 float* P) {
    int tid = blockIdx.x * blockDim.x + threadIdx.x;
    int stride = gridDim.x * blockDim.x;
    for (int idx = tid; idx < 1280; idx += stride) {
        int g = idx & 3, e = idx >> 2, j = e / 10, c = e % 10;
        P[OFF_L0I + idx] = Wih0[(g * 32 + j) * 10 + c];
    }
    for (int idx = tid; idx < 4096; idx += stride) {
        int g = idx & 3, e = idx >> 2, j = e >> 5, k = e & 31;
        P[OFF_L0H + idx] = Whh0[(g * 32 + j) * 32 + k];
        P[OFF_L1I + idx] = Wih1[(g * 32 + j) * 32 + k];
        P[OFF_L1H + idx] = Whh1[(g * 32 + j) * 32 + k];
    }
    for (int idx = tid; idx < 128; idx += stride) {
        int g = idx & 3, j = idx >> 2;
        P[OFF_B0 + idx] = bih0[g * 32 + j] + bhh0[g * 32 + j];
        P[OFF_B1 + idx] = bih1[g * 32 + j] + bhh1[g * 32 + j];
    }
    for (int idx = tid; idx < 2048; idx += stride) {
        int e = idx >> 1, h = idx & 1, ch2 = e >> 5, kk = e & 31;
        P[OFF_FC1W + idx] = fc1w[(2 * ch2 + h) * 32 + kk];
        int m2 = e >> 6, ch = e & 63;
        P[OFF_FC2W2 + idx] = fc2w[(2 * m2 + h) * 64 + ch];
    }
    for (int i = tid; i < 64; i += stride) P[OFF_FC1B + i] = fc1b[i];
    for (int idx = tid; idx < 16384; idx += stride) {
        int k = idx >> 12, r = idx & 4095, e = r >> 1, h = r & 1;
        int co2 = e >> 6, ci = e & 63;
        P[OFF_CWT2 + idx] = convw[k * 4096 + ci * 64 + (2 * co2 + h)];
    }
    for (int i = tid; i < 256; i += stride) P[OFF_CB + i] = convb[i];
    for (int i = tid; i < 32;  i += stride) P[OFF_FC2B + i] = fc2b[i];
    for (int idx = tid; idx < 320; idx += stride) {
        int q = idx & 3, e = idx >> 2, oc2 = e >> 4, m2 = e & 15;
        int oc = 2 * oc2 + (q & 1), m = 2 * m2 + (q >> 1);
        P[OFF_FC3W4 + idx] = fc3w[oc * 32 + m];
    }
    for (int i = tid; i < 10; i += stride) P[OFF_FC3B + i] = fc3b[i];
    for (int idx = tid; idx < 8; idx += stride) {
        int k = idx >> 1;
        float g = gparam[k];
        float denom = g * g + 1e-8f;
        float a = (idx & 1) ? eattr[0] : eattr[STRAIGHT_ATTR_IDX];
        P[OFF_GW + idx] = __expf(-(a * a) / denom);
    }
}

// ---------------- LSTM: 256 thr (4 waves), 128 px/block, 2 px/lane, 8 units/wave ----------------
// Unit loop ROLLED (per-t body ~8 KB, fits I$); c/hn arrays dynamic-indexed -> tiny scratch.
// (256,1): only config observed spill-free (R2/R5 precedent); 512-thr blocks clamp VGPR<=128.
__global__ __launch_bounds__(256, 1)
void lstm_fc1_kernel(const float* __restrict__ x,
                     const float* __restrict__ P,
                     float* __restrict__ feats) {
    __shared__ float4 LW[LSTM_STAGE_F4];   // 55296 B
    __shared__ float  HX[32 * 64];         // 8192 B (total 63488)
    {
        const float4* P4 = (const float4*)P;
        for (int i = threadIdx.x; i < LSTM_STAGE_F4; i += 256) LW[i] = P4[i];
    }
    __syncthreads();

    int p = threadIdx.x & 63;
    int subw = __builtin_amdgcn_readfirstlane((int)(threadIdx.x >> 6)); // 0..3
    int n0 = blockIdx.x * 128 + p;
    int b = n0 >> 16;
    int pix = n0 & (NPIX - 1);
    const float* xb = x + (size_t)b * TT * CC * NPIX + pix;

    const float4* W0I = LW;            // [j*10+c]
    const float4* W0H = LW + 320;      // [j*32+k]
    const float4* W1I = LW + 1344;
    const float4* W1H = LW + 2368;
    const float4* B0  = LW + 3392;
    const float4* B1  = LW + 3424;

    float h0a0[HH], h0a1[HH], h1a0[HH], h1a1[HH];
    float c00[8], c01[8], c10[8], c11[8], hnbuf[8];
#pragma unroll
    for (int k = 0; k < HH; k++) { h0a0[k] = 0.f; h0a1[k] = 0.f; h1a0[k] = 0.f; h1a1[k] = 0.f; }
#pragma unroll
    for (int k = 0; k < 8; k++) { c00[k] = 0.f; c01[k] = 0.f; c10[k] = 0.f; c11[k] = 0.f; }

#pragma unroll 1
    for (int t = 0; t < TT; t++) {
        float xt0[CC], xt1[CC];
#pragma unroll
        for (int c = 0; c < CC; c++) {
            xt0[c] = xb[(size_t)(t * CC + c) * NPIX];
            xt1[c] = xb[(size_t)(t * CC + c) * NPIX + 64];
        }

        // ---- layer 0: my 8 units (rolled), both px ----
#pragma unroll 1
        for (int jj = 0; jj < 8; jj++) {
            int j = subw * 8 + jj;
            float4 z0 = B0[j];
            float4 z1 = z0;
            const float4* wi = W0I + j * CC;
#pragma unroll
            for (int c = 0; c < CC; c++) {
                float4 q = wi[c];
                z0 = fma4(q, xt0[c], z0);
                z1 = fma4(q, xt1[c], z1);
            }
            const float4* wh = W0H + j * HH;
#pragma unroll
            for (int k = 0; k < HH; k++) {
                float4 q = wh[k];
                z0 = fma4(q, h0a0[k], z0);
                z1 = fma4(q, h0a1[k], z1);
            }
            float cn0 = sigf(z0.y) * c00[jj] + sigf(z0.x) * tanhf_(z0.z);
            c00[jj] = cn0;
            HX[j * 64 + p] = sigf(z0.w) * tanhf_(cn0);
            float cn1 = sigf(z1.y) * c01[jj] + sigf(z1.x) * tanhf_(z1.z);
            c01[jj] = cn1;
            hnbuf[jj] = sigf(z1.w) * tanhf_(cn1);
        }
        __syncthreads();
#pragma unroll
        for (int k = 0; k < HH; k++) h0a0[k] = HX[k * 64 + p];
        __syncthreads();
#pragma unroll
        for (int jj = 0; jj < 8; jj++) HX[(subw * 8 + jj) * 64 + p] = hnbuf[jj];
        __syncthreads();
#pragma unroll
        for (int k = 0; k < HH; k++) h0a1[k] = HX[k * 64 + p];
        __syncthreads();

        // ---- layer 1 (rolled) ----
#pragma unroll 1
        for (int jj = 0; jj < 8; jj++) {
            int j = subw * 8 + jj;
            float4 z0 = B1[j];
            float4 z1 = z0;
            const float4* wi = W1I + j * HH;
#pragma unroll
            for (int k = 0; k < HH; k++) {
                float4 q = wi[k];
                z0 = fma4(q, h0a0[k], z0);
                z1 = fma4(q, h0a1[k], z1);
            }
            const float4* wh = W1H + j * HH;
#pragma unroll
            for (int k = 0; k < HH; k++) {
                float4 q = wh[k];
                z0 = fma4(q, h1a0[k], z0);
                z1 = fma4(q, h1a1[k], z1);
            }
            float cn0 = sigf(z0.y) * c10[jj] + sigf(z0.x) * tanhf_(z0.z);
            c10[jj] = cn0;
            HX[j * 64 + p] = sigf(z0.w) * tanhf_(cn0);
            float cn1 = sigf(z1.y) * c11[jj] + sigf(z1.x) * tanhf_(z1.z);
            c11[jj] = cn1;
            hnbuf[jj] = sigf(z1.w) * tanhf_(cn1);
        }
        __syncthreads();
#pragma unroll
        for (int k = 0; k < HH; k++) h1a0[k] = HX[k * 64 + p];
        __syncthreads();
#pragma unroll
        for (int jj = 0; jj < 8; jj++) HX[(subw * 8 + jj) * 64 + p] = hnbuf[jj];
        __syncthreads();
#pragma unroll
        for (int k = 0; k < HH; k++) h1a1[k] = HX[k * 64 + p];
        __syncthreads();
    }

    // ---- fc1 + relu: my 16 channels (8 pairs), both px; uniform global weights ----
    const float2* F1 = (const float2*)(P + OFF_FC1W);
    float* fb = feats + (size_t)b * WIDTH * NPIX + pix;
#pragma unroll 1
    for (int cc = 0; cc < 8; cc++) {
        int ch2 = subw * 8 + cc;
        float ax0 = P[OFF_FC1B + 2 * ch2];
        float ay0 = P[OFF_FC1B + 2 * ch2 + 1];
        float ax1 = ax0, ay1 = ay0;
        const float2* wv = F1 + ch2 * HH;
#pragma unroll
        for (int k = 0; k < HH; k++) {
            float2 q = wv[k];
            ax0 = __builtin_fmaf(q.x, h1a0[k], ax0);
            ay0 = __builtin_fmaf(q.y, h1a0[k], ay0);
            ax1 = __builtin_fmaf(q.x, h1a1[k], ax1);
            ay1 = __builtin_fmaf(q.y, h1a1[k], ay1);
        }
        fb[(size_t)(2 * ch2) * NPIX]          = fmaxf(ax0, 0.f);
        fb[(size_t)(2 * ch2 + 1) * NPIX]      = fmaxf(ay0, 0.f);
        fb[(size_t)(2 * ch2) * NPIX + 64]     = fmaxf(ax1, 0.f);
        fb[(size_t)(2 * ch2 + 1) * NPIX + 64] = fmaxf(ay1, 0.f);
    }
}

// ---------------- fused conv layer: 256 thr, 2 px/lane (vertical pair, 512 px/block) ----------------
__global__ __launch_bounds__(256, 1)
void conv_fused_kernel(const float* __restrict__ Fin, float* __restrict__ Fout,
                       const float* __restrict__ P, int k) {
    __shared__ float4 CW[1024];   // [co2][ci2]
    __shared__ float  CB[64];
    {
        const float4* src = (const float4*)(P + OFF_CWT2 + k * 4096);
        for (int i = threadIdx.x; i < 1024; i += 256) CW[i] = src[i];
        if (threadIdx.x < 64) CB[threadIdx.x] = P[OFF_CB + k * 64 + threadIdx.x];
    }
    __syncthreads();

    int n0 = blockIdx.x * 512 + threadIdx.x;   // grid 256 blocks; px1 = px0 + 256 (next row)
    int b = n0 >> 16;
    int pix0 = n0 & (NPIX - 1);
    int pix1 = pix0 + 256;
    int i0 = pix0 >> 8, j0 = pix0 & 255;
    int i1 = i0 + 1;
    float wstr = P[OFF_GW + 2 * k], wdiag = P[OFF_GW + 2 * k + 1];
    float lf = (j0 > 0) ? 1.f : 0.f, rt = (j0 < 255) ? 1.f : 0.f;
    float fl = lf * wstr, fr = rt * wstr;
    float fu0 = (i0 > 0) ? wstr : 0.f, fd0 = (i0 < 255) ? wstr : 0.f;
    float fu1 = (i1 > 0) ? wstr : 0.f, fd1 = (i1 < 255) ? wstr : 0.f;
    float du0 = (i0 > 0) ? wdiag : 0.f, dd0 = (i0 < 255) ? wdiag : 0.f;
    float du1 = (i1 > 0) ? wdiag : 0.f, dd1 = (i1 < 255) ? wdiag : 0.f;
    float ful0 = du0 * lf, fur0 = du0 * rt, fdl0 = dd0 * lf, fdr0 = dd0 * rt;
    float ful1 = du1 * lf, fur1 = du1 * rt, fdl1 = dd1 * lf, fdr1 = dd1 * rt;

    const float* fb = Fin + (size_t)b * WIDTH * NPIX;
    float u0[WIDTH], u1[WIDTH];
#pragma unroll
    for (int ch = 0; ch < WIDTH; ch++) {
        const float* yc0 = fb + (size_t)ch * NPIX + pix0;
        float v0 = yc0[0];
        v0 += fu0 * yc0[-256] + fd0 * yc0[256] + fl * yc0[-1] + fr * yc0[1];
        v0 += ful0 * yc0[-257] + fur0 * yc0[-255] + fdl0 * yc0[255] + fdr0 * yc0[257];
        u0[ch] = v0;
        const float* yc1 = yc0 + 256;
        float v1 = yc1[0];
        v1 += fu1 * yc1[-256] + fd1 * yc1[256] + fl * yc1[-1] + fr * yc1[1];
        v1 += ful1 * yc1[-257] + fur1 * yc1[-255] + fdl1 * yc1[255] + fdr1 * yc1[257];
        u1[ch] = v1;
    }

    float* ob = Fout + (size_t)b * WIDTH * NPIX;
#pragma unroll 1
    for (int co2 = 0; co2 < 32; co2++) {
        float bx = CB[2 * co2], by = CB[2 * co2 + 1];
        float ax0 = bx, ay0 = by, ax1 = bx, ay1 = by;
        const float4* wv = CW + co2 * 32;
#pragma unroll
        for (int ci2 = 0; ci2 < 32; ci2++) {
            float4 q = wv[ci2];
            float a0 = u0[2 * ci2], a1 = u0[2 * ci2 + 1];
            float b0 = u1[2 * ci2], b1 = u1[2 * ci2 + 1];
            ax0 = __builtin_fmaf(q.x, a0, ax0); ax0 = __builtin_fmaf(q.z, a1, ax0);
            ay0 = __builtin_fmaf(q.y, a0, ay0); ay0 = __builtin_fmaf(q.w, a1, ay0);
            ax1 = __builtin_fmaf(q.x, b0, ax1); ax1 = __builtin_fmaf(q.z, b1, ax1);
            ay1 = __builtin_fmaf(q.y, b0, ay1); ay1 = __builtin_fmaf(q.w, b1, ay1);
        }
        ob[(size_t)(2 * co2) * NPIX + pix0]     = fmaxf(ax0, 0.f);
        ob[(size_t)(2 * co2 + 1) * NPIX + pix0] = fmaxf(ay0, 0.f);
        ob[(size_t)(2 * co2) * NPIX + pix1]     = fmaxf(ax1, 0.f);
        ob[(size_t)(2 * co2 + 1) * NPIX + pix1] = fmaxf(ay1, 0.f);
    }
}

// ---------------- last conv (no relu) + fc2/fc3 head (1 px/thread) ----------------
__global__ __launch_bounds__(256, 1)
void conv_head_kernel(const float* __restrict__ Fin, const float* __restrict__ P,
                      float* __restrict__ out) {
    const int k = 3;
    __shared__ float4 CW3[1024];
    __shared__ float  CB3[64];
    __shared__ float4 F2W[512];
    __shared__ float  F2B[32];
    __shared__ float4 F3W[80];
    __shared__ float  F3B[12];
    {
        const float4* s1 = (const float4*)(P + OFF_CWT2 + k * 4096);
        for (int i = threadIdx.x; i < 1024; i += 256) CW3[i] = s1[i];
        const float4* s2 = (const float4*)(P + OFF_FC2W2);
        for (int i = threadIdx.x; i < 512; i += 256) F2W[i] = s2[i];
        const float4* s3 = (const float4*)(P + OFF_FC3W4);
        if (threadIdx.x < 80) F3W[threadIdx.x] = s3[threadIdx.x];
        if (threadIdx.x < 64) CB3[threadIdx.x] = P[OFF_CB + k * 64 + threadIdx.x];
        if (threadIdx.x < 32) F2B[threadIdx.x] = P[OFF_FC2B + threadIdx.x];
        if (threadIdx.x < 10) F3B[threadIdx.x] = P[OFF_FC3B + threadIdx.x];
    }
    __syncthreads();

    int n = blockIdx.x * 256 + threadIdx.x;
    int b = n >> 16;
    int pix = n & (NPIX - 1);
    int i = pix >> 8, j = pix & 255;
    float wstr = P[OFF_GW + 2 * k], wdiag = P[OFF_GW + 2 * k + 1];
    float fu = (i > 0) ? wstr : 0.f, fd = (i < 255) ? wstr : 0.f;
    float fl = (j > 0) ? wstr : 0.f, fr = (j < 255) ? wstr : 0.f;
    float ful = (i > 0 && j > 0) ? wdiag : 0.f, fur = (i > 0 && j < 255) ? wdiag : 0.f;
    float fdl = (i < 255 && j > 0) ? wdiag : 0.f, fdr = (i < 255 && j < 255) ? wdiag : 0.f;

    const float* fb = Fin + (size_t)b * WIDTH * NPIX + pix;
    float u[WIDTH];
#pragma unroll
    for (int ch = 0; ch < WIDTH; ch++) {
        const float* yc = fb + (size_t)ch * NPIX;
        float v = yc[0];
        v += fu * yc[-256] + fd * yc[256] + fl * yc[-1] + fr * yc[1];
        v += ful * yc[-257] + fur * yc[-255] + fdl * yc[255] + fdr * yc[257];
        u[ch] = v;
    }

    float f[WIDTH];
#pragma unroll
    for (int co2 = 0; co2 < 32; co2++) {
        float ax = CB3[2 * co2], ay = CB3[2 * co2 + 1];
        const float4* wv = CW3 + co2 * 32;
#pragma unroll
        for (int ci2 = 0; ci2 < 32; ci2++) {
            float4 q = wv[ci2];
            float a0 = u[2 * ci2], a1 = u[2 * ci2 + 1];
            ax = __builtin_fmaf(q.x, a0, ax); ax = __builtin_fmaf(q.z, a1, ax);
            ay = __builtin_fmaf(q.y, a0, ay); ay = __builtin_fmaf(q.w, a1, ay);
        }
        f[2 * co2] = ax; f[2 * co2 + 1] = ay;
    }

    float2 oo[5];
#pragma unroll
    for (int oc2 = 0; oc2 < 5; oc2++) oo[oc2] = make_float2(F3B[2 * oc2], F3B[2 * oc2 + 1]);
#pragma unroll 1
    for (int m2 = 0; m2 < 16; m2++) {
        float ax = F2B[2 * m2], ay = F2B[2 * m2 + 1];
        const float4* wv = F2W + m2 * 32;
#pragma unroll
        for (int ch2 = 0; ch2 < 32; ch2++) {
            float4 q = wv[ch2];
            ax = __builtin_fmaf(q.x, f[2 * ch2], ax); ax = __builtin_fmaf(q.z, f[2 * ch2 + 1], ax);
            ay = __builtin_fmaf(q.y, f[2 * ch2], ay); ay = __builtin_fmaf(q.w, f[2 * ch2 + 1], ay);
        }
        ax = fmaxf(ax, 0.f); ay = fmaxf(ay, 0.f);
#pragma unroll
        for (int oc2 = 0; oc2 < 5; oc2++) {
            float4 q = F3W[oc2 * 16 + m2];
            oo[oc2].x += q.x * ax + q.z * ay;
            oo[oc2].y += q.y * ax + q.w * ay;
        }
    }
    float* ob = out + (size_t)b * OUTC * NPIX + pix;
#pragma unroll
    for (int oc2 = 0; oc2 < 5; oc2++) {
        ob[(size_t)(2 * oc2) * NPIX]     = oo[oc2].x;
        ob[(size_t)(2 * oc2 + 1) * NPIX] = oo[oc2].y;
    }
}

extern "C" void kernel_launch(void* const* d_in, const int* in_sizes, int n_in,
                              void* d_out, int out_size, void* d_ws, size_t ws_size,
                              hipStream_t stream) {
    const float* x     = (const float*)d_in[0];
    const float* eattr = (const float*)d_in[3];
    const float* Wih0  = (const float*)d_in[4];
    const float* Whh0  = (const float*)d_in[5];
    const float* bih0  = (const float*)d_in[6];
    const float* bhh0  = (const float*)d_in[7];
    const float* Wih1  = (const float*)d_in[8];
    const float* Whh1  = (const float*)d_in[9];
    const float* bih1  = (const float*)d_in[10];
    const float* bhh1  = (const float*)d_in[11];
    const float* fc1w  = (const float*)d_in[12];
    const float* fc1b  = (const float*)d_in[13];
    const float* convw = (const float*)d_in[14];
    const float* convb = (const float*)d_in[15];
    const float* gparam= (const float*)d_in[16];
    const float* fc2w  = (const float*)d_in[17];
    const float* fc2b  = (const float*)d_in[18];
    const float* fc3w  = (const float*)d_in[19];
    const float* fc3b  = (const float*)d_in[20];

    float* P  = (float*)d_ws;
    float* FA = P + OFF_FEATS_A;
    float* FB = P + OFF_FEATS_B;

    prep_kernel<<<64, 256, 0, stream>>>(Wih0, Whh0, bih0, bhh0, Wih1, Whh1, bih1, bhh1,
                                        fc1w, fc1b, convw, convb, fc2w, fc2b, fc3w, fc3b,
                                        gparam, eattr, P);
    lstm_fc1_kernel<<<1024, 256, 0, stream>>>(x, P, FA);
    conv_fused_kernel<<<256, 256, 0, stream>>>(FA, FB, P, 0);
    conv_fused_kernel<<<256, 256, 0, stream>>>(FB, FA, P, 1);
    conv_fused_kernel<<<256, 256, 0, stream>>>(FA, FB, P, 2);
    conv_head_kernel<<<512, 256, 0, stream>>>(FB, P, (float*)d_out);
}

// Round 8
// 637.810 us; speedup vs baseline: 1.3967x; 1.3967x over previous
//
#include <hip/hip_runtime.h>
#include <hip/hip_bf16.h>

#define NPIX   65536
#define TT     5
#define CC     10
#define HH     32
#define WIDTH  64
#define KW     32
#define OUTC   10

// ---- workspace layout (float offsets) ----
// LSTM weights k-major gate-packed for SGPR streaming: [k][j][g], g=(i,f,g,o)
#define OFF_L0I    0        // 1280  [c][j][g]
#define OFF_L0H    1280     // 4096  [k][j][g]
#define OFF_L1I    5376     // 4096
#define OFF_L1H    9472     // 4096
#define OFF_B0     13568    // 128   [j][g]
#define OFF_B1     13696    // 128
#define OFF_FC1W   13824    // 2048  [k][ch]
#define OFF_FC1B   15872    // 64
#define OFF_CWT2   16384    // 16384 [k][co2][ci] float2 (conv, LDS-staged as in R5)
#define OFF_CB     32768    // 256
#define OFF_FC2W2  33024    // 2048  [m2][ch] float2
#define OFF_FC2B   35072    // 32
#define OFF_FC3W4  35104    // 320   [oc2][m2] float4
#define OFF_FC3B   35424    // 16
#define OFF_GW     35440    // 8
#define OFF_FEATS_A 36864
#define OFF_FEATS_B (36864 + 8388608)

#define STRAIGHT_ATTR_IDX (65025 * 3)

__device__ __forceinline__ float sigf(float x)  { return 1.0f / (1.0f + __expf(-x)); }
__device__ __forceinline__ float tanhf_(float x){ return 1.0f - 2.0f / (__expf(2.0f * x) + 1.0f); }

// ---------------- prep: pack params ----------------
__global__ __launch_bounds__(256, 1)
void prep_kernel(const float* Wih0, const float* Whh0,
                 const float* bih0, const float* bhh0,
                 const float* Wih1, const float* Whh1,
                 const float* bih1, const float* bhh1,
                 const float* fc1w, const float* fc1b,
                 const float* convw, const float* convb,
                 const float* fc2w, const float* fc2b,
                 const float* fc3w, const float* fc3b,
                 const float* gparam, const float* eattr,
                 float* P) {
    int tid = blockIdx.x * blockDim.x + threadIdx.x;
    int stride = gridDim.x * blockDim.x;
    // LSTM k-major: [k][j][g] <- W[(g*32+j)*K + k]
    for (int idx = tid; idx < 1280; idx += stride) {
        int g = idx & 3, j = (idx >> 2) & 31, c = idx >> 7;
        P[OFF_L0I + idx] = Wih0[(g * 32 + j) * 10 + c];
    }
    for (int idx = tid; idx < 4096; idx += stride) {
        int g = idx & 3, j = (idx >> 2) & 31, k = idx >> 7;
        P[OFF_L0H + idx] = Whh0[(g * 32 + j) * 32 + k];
        P[OFF_L1I + idx] = Wih1[(g * 32 + j) * 32 + k];
        P[OFF_L1H + idx] = Whh1[(g * 32 + j) * 32 + k];
    }
    for (int idx = tid; idx < 128; idx += stride) {
        int g = idx & 3, j = idx >> 2;
        P[OFF_B0 + idx] = bih0[g * 32 + j] + bhh0[g * 32 + j];
        P[OFF_B1 + idx] = bih1[g * 32 + j] + bhh1[g * 32 + j];
    }
    // fc1 k-major [k][ch]
    for (int idx = tid; idx < 2048; idx += stride) {
        int ch = idx & 63, k = idx >> 6;
        P[OFF_FC1W + idx] = fc1w[ch * 32 + k];
    }
    for (int i = tid; i < 64; i += stride) P[OFF_FC1B + i] = fc1b[i];
    // conv [k][co2][ci] float2 (same as R5)
    for (int idx = tid; idx < 16384; idx += stride) {
        int k = idx >> 12, r = idx & 4095, e = r >> 1, h = r & 1;
        int co2 = e >> 6, ci = e & 63;
        P[OFF_CWT2 + idx] = convw[k * 4096 + ci * 64 + (2 * co2 + h)];
    }
    for (int i = tid; i < 256; i += stride) P[OFF_CB + i] = convb[i];
    for (int idx = tid; idx < 2048; idx += stride) {
        int e = idx >> 1, h = idx & 1, m2 = e >> 6, ch = e & 63;
        P[OFF_FC2W2 + idx] = fc2w[(2 * m2 + h) * 64 + ch];
    }
    for (int i = tid; i < 32;  i += stride) P[OFF_FC2B + i] = fc2b[i];
    for (int idx = tid; idx < 320; idx += stride) {
        int q = idx & 3, e = idx >> 2, oc2 = e >> 4, m2 = e & 15;
        int oc = 2 * oc2 + (q & 1), m = 2 * m2 + (q >> 1);
        P[OFF_FC3W4 + idx] = fc3w[oc * 32 + m];
    }
    for (int i = tid; i < 10; i += stride) P[OFF_FC3B + i] = fc3b[i];
    for (int idx = tid; idx < 8; idx += stride) {
        int k = idx >> 1;
        float g = gparam[k];
        float denom = g * g + 1e-8f;
        float a = (idx & 1) ? eattr[0] : eattr[STRAIGHT_ATTR_IDX];
        P[OFF_GW + idx] = __expf(-(a * a) / denom);
    }
}

// ---------------- LSTM: 128 thr, 1 px/lane, whole LSTM per lane ----------------
// Weights are wave-uniform -> SGPR via s_load (k-major [k][j][g] rows of 128 floats);
// v_fmac takes the SGPR directly (1 SGPR/VALU-inst limit respected).
// h/x state lives in per-lane LDS columns (conflict-free, no barriers needed —
// each lane touches only its own column). c/z stay in static registers.
__global__ __launch_bounds__(128, 1)
void lstm_fc1_kernel(const float* __restrict__ x,
                     const float* __restrict__ P,
                     float* __restrict__ feats) {
    __shared__ float XS[CC * 128];   // 5120 B
    __shared__ float H0[HH * 128];   // 16384 B
    __shared__ float H1[HH * 128];   // 16384 B  (total 37888)

    int tid = threadIdx.x;
    int n = blockIdx.x * 128 + tid;
    int b = n >> 16;
    int pix = n & (NPIX - 1);
    const float* xb = x + (size_t)b * TT * CC * NPIX + pix;

    float4 z[HH];
    float c0[HH], c1[HH];
#pragma unroll
    for (int j = 0; j < HH; j++) {
        c0[j] = 0.f; c1[j] = 0.f;
        H0[j * 128 + tid] = 0.f;
        H1[j * 128 + tid] = 0.f;
    }

#pragma unroll 1
    for (int t = 0; t < TT; t++) {
        // stage x(t) for this lane
#pragma unroll
        for (int c = 0; c < CC; c++)
            XS[c * 128 + tid] = xb[(size_t)(t * CC + c) * NPIX];

        // ---- layer 0 ----
#pragma unroll
        for (int j = 0; j < HH; j++) z[j] = *(const float4*)(P + OFF_B0 + 4 * j);
#pragma unroll 1
        for (int c = 0; c < CC; c++) {
            float xv = XS[c * 128 + tid];
            const float* wr = P + OFF_L0I + c * 128;
#pragma unroll
            for (int j = 0; j < HH; j++) {
                z[j].x = __builtin_fmaf(wr[4 * j + 0], xv, z[j].x);
                z[j].y = __builtin_fmaf(wr[4 * j + 1], xv, z[j].y);
                z[j].z = __builtin_fmaf(wr[4 * j + 2], xv, z[j].z);
                z[j].w = __builtin_fmaf(wr[4 * j + 3], xv, z[j].w);
            }
        }
#pragma unroll 1
        for (int k = 0; k < HH; k++) {
            float hv = H0[k * 128 + tid];
            const float* wr = P + OFF_L0H + k * 128;
#pragma unroll
            for (int j = 0; j < HH; j++) {
                z[j].x = __builtin_fmaf(wr[4 * j + 0], hv, z[j].x);
                z[j].y = __builtin_fmaf(wr[4 * j + 1], hv, z[j].y);
                z[j].z = __builtin_fmaf(wr[4 * j + 2], hv, z[j].z);
                z[j].w = __builtin_fmaf(wr[4 * j + 3], hv, z[j].w);
            }
        }
#pragma unroll
        for (int j = 0; j < HH; j++) {
            float cn = sigf(z[j].y) * c0[j] + sigf(z[j].x) * tanhf_(z[j].z);
            c0[j] = cn;
            H0[j * 128 + tid] = sigf(z[j].w) * tanhf_(cn);   // own column only
        }

        // ---- layer 1 ----
#pragma unroll
        for (int j = 0; j < HH; j++) z[j] = *(const float4*)(P + OFF_B1 + 4 * j);
#pragma unroll 1
        for (int k = 0; k < HH; k++) {
            float hv = H0[k * 128 + tid];
            const float* wr = P + OFF_L1I + k * 128;
#pragma unroll
            for (int j = 0; j < HH; j++) {
                z[j].x = __builtin_fmaf(wr[4 * j + 0], hv, z[j].x);
                z[j].y = __builtin_fmaf(wr[4 * j + 1], hv, z[j].y);
                z[j].z = __builtin_fmaf(wr[4 * j + 2], hv, z[j].z);
                z[j].w = __builtin_fmaf(wr[4 * j + 3], hv, z[j].w);
            }
        }
#pragma unroll 1
        for (int k = 0; k < HH; k++) {
            float hv = H1[k * 128 + tid];           // old h1 (updated after loop)
            const float* wr = P + OFF_L1H + k * 128;
#pragma unroll
            for (int j = 0; j < HH; j++) {
                z[j].x = __builtin_fmaf(wr[4 * j + 0], hv, z[j].x);
                z[j].y = __builtin_fmaf(wr[4 * j + 1], hv, z[j].y);
                z[j].z = __builtin_fmaf(wr[4 * j + 2], hv, z[j].z);
                z[j].w = __builtin_fmaf(wr[4 * j + 3], hv, z[j].w);
            }
        }
#pragma unroll
        for (int j = 0; j < HH; j++) {
            float cn = sigf(z[j].y) * c1[j] + sigf(z[j].x) * tanhf_(z[j].z);
            c1[j] = cn;
            H1[j * 128 + tid] = sigf(z[j].w) * tanhf_(cn);
        }
    }

    // ---- fc1 + relu (k-major SGPR weights) ----
    float f[WIDTH];
#pragma unroll
    for (int ch = 0; ch < WIDTH; ch++) f[ch] = P[OFF_FC1B + ch];
#pragma unroll 1
    for (int k = 0; k < HH; k++) {
        float hv = H1[k * 128 + tid];
        const float* wr = P + OFF_FC1W + k * 64;
#pragma unroll
        for (int ch = 0; ch < WIDTH; ch++)
            f[ch] = __builtin_fmaf(wr[ch], hv, f[ch]);
    }
    float* fb = feats + (size_t)b * WIDTH * NPIX + pix;
#pragma unroll
    for (int ch = 0; ch < WIDTH; ch++)
        fb[(size_t)ch * NPIX] = fmaxf(f[ch], 0.f);
}

// ---------------- fused conv layer (R5-proven shape: 256 thr, 1 px/lane) ----------------
__global__ __launch_bounds__(256, 1)
void conv_fused_kernel(const float* __restrict__ Fin, float* __restrict__ Fout,
                       const float* __restrict__ P, int k) {
    __shared__ float4 CW[1024];   // [co2][ci2]
    __shared__ float  CB[64];
    {
        const float4* src = (const float4*)(P + OFF_CWT2 + k * 4096);
        for (int i = threadIdx.x; i < 1024; i += 256) CW[i] = src[i];
        if (threadIdx.x < 64) CB[threadIdx.x] = P[OFF_CB + k * 64 + threadIdx.x];
    }
    __syncthreads();

    int n = blockIdx.x * 256 + threadIdx.x;
    int b = n >> 16;
    int pix = n & (NPIX - 1);
    int i = pix >> 8, j = pix & 255;
    float wstr = P[OFF_GW + 2 * k], wdiag = P[OFF_GW + 2 * k + 1];
    float fu = (i > 0) ? wstr : 0.f, fd = (i < 255) ? wstr : 0.f;
    float fl = (j > 0) ? wstr : 0.f, fr = (j < 255) ? wstr : 0.f;
    float ful = (i > 0 && j > 0) ? wdiag : 0.f, fur = (i > 0 && j < 255) ? wdiag : 0.f;
    float fdl = (i < 255 && j > 0) ? wdiag : 0.f, fdr = (i < 255 && j < 255) ? wdiag : 0.f;

    const float* fb = Fin + (size_t)b * WIDTH * NPIX + pix;
    float u[WIDTH];
#pragma unroll
    for (int ch = 0; ch < WIDTH; ch++) {
        const float* yc = fb + (size_t)ch * NPIX;
        float v = yc[0];
        v += fu * yc[-256] + fd * yc[256] + fl * yc[-1] + fr * yc[1];
        v += ful * yc[-257] + fur * yc[-255] + fdl * yc[255] + fdr * yc[257];
        u[ch] = v;
    }

    float* ob = Fout + (size_t)b * WIDTH * NPIX + pix;
#pragma unroll 1
    for (int co2 = 0; co2 < 32; co2++) {
        float ax = CB[2 * co2], ay = CB[2 * co2 + 1];
        const float4* wv = CW + co2 * 32;
#pragma unroll
        for (int ci2 = 0; ci2 < 32; ci2++) {
            float4 q = wv[ci2];
            float a0 = u[2 * ci2], a1 = u[2 * ci2 + 1];
            ax = __builtin_fmaf(q.x, a0, ax); ax = __builtin_fmaf(q.z, a1, ax);
            ay = __builtin_fmaf(q.y, a0, ay); ay = __builtin_fmaf(q.w, a1, ay);
        }
        ob[(size_t)(2 * co2) * NPIX]     = fmaxf(ax, 0.f);
        ob[(size_t)(2 * co2 + 1) * NPIX] = fmaxf(ay, 0.f);
    }
}

// ---------------- last conv (no relu) + fc2/fc3 head ----------------
__global__ __launch_bounds__(256, 1)
void conv_head_kernel(const float* __restrict__ Fin, const float* __restrict__ P,
                      float* __restrict__ out) {
    const int k = 3;
    __shared__ float4 CW3[1024];
    __shared__ float  CB3[64];
    __shared__ float4 F2W[512];
    __shared__ float  F2B[32];
    __shared__ float4 F3W[80];
    __shared__ float  F3B[12];
    {
        const float4* s1 = (const float4*)(P + OFF_CWT2 + k * 4096);
        for (int i = threadIdx.x; i < 1024; i += 256) CW3[i] = s1[i];
        const float4* s2 = (const float4*)(P + OFF_FC2W2);
        for (int i = threadIdx.x; i < 512; i += 256) F2W[i] = s2[i];
        const float4* s3 = (const float4*)(P + OFF_FC3W4);
        if (threadIdx.x < 80) F3W[threadIdx.x] = s3[threadIdx.x];
        if (threadIdx.x < 64) CB3[threadIdx.x] = P[OFF_CB + k * 64 + threadIdx.x];
        if (threadIdx.x < 32) F2B[threadIdx.x] = P[OFF_FC2B + threadIdx.x];
        if (threadIdx.x < 10) F3B[threadIdx.x] = P[OFF_FC3B + threadIdx.x];
    }
    __syncthreads();

    int n = blockIdx.x * 256 + threadIdx.x;
    int b = n >> 16;
    int pix = n & (NPIX - 1);
    int i = pix >> 8, j = pix & 255;
    float wstr = P[OFF_GW + 2 * k], wdiag = P[OFF_GW + 2 * k + 1];
    float fu = (i > 0) ? wstr : 0.f, fd = (i < 255) ? wstr : 0.f;
    float fl = (j > 0) ? wstr : 0.f, fr = (j < 255) ? wstr : 0.f;
    float ful = (i > 0 && j > 0) ? wdiag : 0.f, fur = (i > 0 && j < 255) ? wdiag : 0.f;
    float fdl = (i < 255 && j > 0) ? wdiag : 0.f, fdr = (i < 255 && j < 255) ? wdiag : 0.f;

    const float* fb = Fin + (size_t)b * WIDTH * NPIX + pix;
    float u[WIDTH];
#pragma unroll
    for (int ch = 0; ch < WIDTH; ch++) {
        const float* yc = fb + (size_t)ch * NPIX;
        float v = yc[0];
        v += fu * yc[-256] + fd * yc[256] + fl * yc[-1] + fr * yc[1];
        v += ful * yc[-257] + fur * yc[-255] + fdl * yc[255] + fdr * yc[257];
        u[ch] = v;
    }

    float f[WIDTH];
#pragma unroll
    for (int co2 = 0; co2 < 32; co2++) {
        float ax = CB3[2 * co2], ay = CB3[2 * co2 + 1];
        const float4* wv = CW3 + co2 * 32;
#pragma unroll
        for (int ci2 = 0; ci2 < 32; ci2++) {
            float4 q = wv[ci2];
            float a0 = u[2 * ci2], a1 = u[2 * ci2 + 1];
            ax = __builtin_fmaf(q.x, a0, ax); ax = __builtin_fmaf(q.z, a1, ax);
            ay = __builtin_fmaf(q.y, a0, ay); ay = __builtin_fmaf(q.w, a1, ay);
        }
        f[2 * co2] = ax; f[2 * co2 + 1] = ay;
    }

    float2 oo[5];
#pragma unroll
    for (int oc2 = 0; oc2 < 5; oc2++) oo[oc2] = make_float2(F3B[2 * oc2], F3B[2 * oc2 + 1]);
#pragma unroll 1
    for (int m2 = 0; m2 < 16; m2++) {
        float ax = F2B[2 * m2], ay = F2B[2 * m2 + 1];
        const float4* wv = F2W + m2 * 32;
#pragma unroll
        for (int ch2 = 0; ch2 < 32; ch2++) {
            float4 q = wv[ch2];
            ax = __builtin_fmaf(q.x, f[2 * ch2], ax); ax = __builtin_fmaf(q.z, f[2 * ch2 + 1], ax);
            ay = __builtin_fmaf(q.y, f[2 * ch2], ay); ay = __builtin_fmaf(q.w, f[2 * ch2 + 1], ay);
        }
        ax = fmaxf(ax, 0.f); ay = fmaxf(ay, 0.f);
#pragma unroll
        for (int oc2 = 0; oc2 < 5; oc2++) {
            float4 q = F3W[oc2 * 16 + m2];
            oo[oc2].x += q.x * ax + q.z * ay;
            oo[oc2].y += q.y * ax + q.w * ay;
        }
    }
    float* ob = out + (size_t)b * OUTC * NPIX + pix;
#pragma unroll
    for (int oc2 = 0; oc2 < 5; oc2++) {
        ob[(size_t)(2 * oc2) * NPIX]     = oo[oc2].x;
        ob[(size_t)(2 * oc2 + 1) * NPIX] = oo[oc2].y;
    }
}

extern "C" void kernel_launch(void* const* d_in, const int* in_sizes, int n_in,
                              void* d_out, int out_size, void* d_ws, size_t ws_size,
                              hipStream_t stream) {
    const float* x     = (const float*)d_in[0];
    const float* eattr = (const float*)d_in[3];
    const float* Wih0  = (const float*)d_in[4];
    const float* Whh0  = (const float*)d_in[5];
    const float* bih0  = (const float*)d_in[6];
    const float* bhh0  = (const float*)d_in[7];
    const float* Wih1  = (const float*)d_in[8];
    const float* Whh1  = (const float*)d_in[9];
    const float* bih1  = (const float*)d_in[10];
    const float* bhh1  = (const float*)d_in[11];
    const float* fc1w  = (const float*)d_in[12];
    const float* fc1b  = (const float*)d_in[13];
    const float* convw = (const float*)d_in[14];
    const float* convb = (const float*)d_in[15];
    const float* gparam= (const float*)d_in[16];
    const float* fc2w  = (const float*)d_in[17];
    const float* fc2b  = (const float*)d_in[18];
    const float* fc3w  = (const float*)d_in[19];
    const float* fc3b  = (const float*)d_in[20];

    float* P  = (float*)d_ws;
    float* FA = P + OFF_FEATS_A;
    float* FB = P + OFF_FEATS_B;

    prep_kernel<<<64, 256, 0, stream>>>(Wih0, Whh0, bih0, bhh0, Wih1, Whh1, bih1, bhh1,
                                        fc1w, fc1b, convw, convb, fc2w, fc2b, fc3w, fc3b,
                                        gparam, eattr, P);
    lstm_fc1_kernel<<<1024, 128, 0, stream>>>(x, P, FA);
    conv_fused_kernel<<<512, 256, 0, stream>>>(FA, FB, P, 0);
    conv_fused_kernel<<<512, 256, 0, stream>>>(FB, FA, P, 1);
    conv_fused_kernel<<<512, 256, 0, stream>>>(FA, FB, P, 2);
    conv_head_kernel<<<512, 256, 0, stream>>>(FB, P, (float*)d_out);
}